// Round 1
// baseline (353.185 us; speedup 1.0000x reference)
//
#include <hip/hip_runtime.h>
#include <hip/hip_bf16.h>
#include <math.h>

// Graph attention layer:
//   scores[e]   = dot(embs[r0[e]], embs[r1[e]])            (d=128)
//   seg softmax of scores over r0
//   out[n]      = sum_{e: r0[e]==n} attn[e] * embs[r1[e]]
//
// Strategy: counting-sort CSR (no fp atomics), then one wave per node doing
// an online-softmax weighted accumulation (float2 per lane, 64*2 = 128).

#define WAVE 64

// ---------------- kernel 1: per-edge scores + degree counts -----------------
__global__ void scores_kernel(const float* __restrict__ embs,
                              const int* __restrict__ ratings,
                              float* __restrict__ scores,
                              int* __restrict__ counts,
                              int n_edges) {
    int gid  = blockIdx.x * blockDim.x + threadIdx.x;
    int e    = gid >> 6;           // one wave per edge
    int lane = threadIdx.x & 63;
    if (e >= n_edges) return;
    int r0 = ratings[2 * e];
    int r1 = ratings[2 * e + 1];
    const float2* a = (const float2*)(embs + (size_t)r0 * 128);
    const float2* b = (const float2*)(embs + (size_t)r1 * 128);
    float2 av = a[lane];
    float2 bv = b[lane];
    float s = av.x * bv.x + av.y * bv.y;
    // wave-64 reduction
    #pragma unroll
    for (int off = 32; off > 0; off >>= 1)
        s += __shfl_down(s, off, 64);
    if (lane == 0) {
        scores[e] = s;
        atomicAdd(&counts[r0], 1);
    }
}

// ---------------- kernel 2: single-block exclusive scan ---------------------
__global__ void scan_kernel(const int* __restrict__ counts,
                            int* __restrict__ offsets,
                            int* __restrict__ cursor,
                            int n) {
    __shared__ int temp[1024];
    __shared__ int s_running;
    int tid = threadIdx.x;
    if (tid == 0) s_running = 0;
    for (int base = 0; base < n; base += 1024) {
        __syncthreads();
        int i = base + tid;
        int v = (i < n) ? counts[i] : 0;
        temp[tid] = v;
        __syncthreads();
        int val = v;
        for (int off = 1; off < 1024; off <<= 1) {
            int t = (tid >= off) ? temp[tid - off] : 0;
            __syncthreads();
            val += t;
            temp[tid] = val;
            __syncthreads();
        }
        int excl = val - v;           // exclusive within tile
        int running = s_running;
        if (i < n) {
            offsets[i] = running + excl;
            cursor[i]  = running + excl;
        }
        __syncthreads();
        if (tid == 1023) s_running = running + val;  // val == tile inclusive total at tid 1023
    }
    __syncthreads();
    if (tid == 0) offsets[n] = s_running;
}

// ---------------- kernel 3: scatter edge ids into CSR order -----------------
__global__ void scatter_kernel(const int* __restrict__ ratings,
                               int* __restrict__ cursor,
                               int* __restrict__ perm,
                               int n_edges) {
    int e = blockIdx.x * blockDim.x + threadIdx.x;
    if (e >= n_edges) return;
    int r0 = ratings[2 * e];
    int pos = atomicAdd(&cursor[r0], 1);
    perm[pos] = e;
}

// ---------------- kernel 4: per-node online softmax + weighted sum ----------
__global__ void node_kernel(const float* __restrict__ embs,
                            const int* __restrict__ ratings,
                            const float* __restrict__ scores,
                            const int* __restrict__ offsets,
                            const int* __restrict__ perm,
                            float* __restrict__ out,
                            int node_num) {
    int gid  = blockIdx.x * blockDim.x + threadIdx.x;
    int n    = gid >> 6;           // one wave per node
    int lane = threadIdx.x & 63;
    if (n >= node_num) return;
    int start = offsets[n];
    int end   = offsets[n + 1];

    float m = -INFINITY;
    float l = 0.f;
    float2 acc = make_float2(0.f, 0.f);

    for (int i = start; i < end; ++i) {
        int e = perm[i];                       // broadcast scalar loads
        float s = scores[e];
        int r1 = ratings[2 * e + 1];
        float2 v = ((const float2*)(embs + (size_t)r1 * 128))[lane];
        float m_new = fmaxf(m, s);
        float alpha = expf(m - m_new);         // 0 when m == -inf
        float p     = expf(s - m_new);
        l = l * alpha + p;
        acc.x = acc.x * alpha + p * v.x;
        acc.y = acc.y * alpha + p * v.y;
        m = m_new;
    }
    float inv = (end > start) ? 1.f / l : 0.f;
    float2 o = make_float2(acc.x * inv, acc.y * inv);
    ((float2*)(out + (size_t)n * 128))[lane] = o;
}

// ---------------------------------------------------------------------------
extern "C" void kernel_launch(void* const* d_in, const int* in_sizes, int n_in,
                              void* d_out, int out_size, void* d_ws, size_t ws_size,
                              hipStream_t stream) {
    const float* embs    = (const float*)d_in[0];
    const int*   ratings = (const int*)d_in[1];
    const int d        = 128;
    const int node_num = in_sizes[0] / d;
    const int n_edges  = in_sizes[1] / 2;
    float* out = (float*)d_out;

    // workspace carve-up (256 B aligned)
    auto align256 = [](size_t x) { return (x + 255) & ~(size_t)255; };
    char* ws = (char*)d_ws;
    float* scores  = (float*)ws;                    ws += align256((size_t)n_edges * 4);
    int*   counts  = (int*)ws;                      ws += align256((size_t)node_num * 4);
    int*   offsets = (int*)ws;                      ws += align256((size_t)(node_num + 1) * 4);
    int*   cursor  = (int*)ws;                      ws += align256((size_t)node_num * 4);
    int*   perm    = (int*)ws;                      ws += align256((size_t)n_edges * 4);

    hipMemsetAsync(counts, 0, (size_t)node_num * 4, stream);

    {   // one wave per edge
        int threads = 256;
        long long total = (long long)n_edges * WAVE;
        int blocks = (int)((total + threads - 1) / threads);
        scores_kernel<<<blocks, threads, 0, stream>>>(embs, ratings, scores, counts, n_edges);
    }
    scan_kernel<<<1, 1024, 0, stream>>>(counts, offsets, cursor, node_num);
    {
        int threads = 256;
        int blocks = (n_edges + threads - 1) / threads;
        scatter_kernel<<<blocks, threads, 0, stream>>>(ratings, cursor, perm, n_edges);
    }
    {   // one wave per node
        int threads = 256;
        long long total = (long long)node_num * WAVE;
        int blocks = (int)((total + threads - 1) / threads);
        node_kernel<<<blocks, threads, 0, stream>>>(embs, ratings, scores, offsets, perm, out, node_num);
    }
}

// Round 2
// 207.617 us; speedup vs baseline: 1.7011x; 1.7011x over previous
//
#include <hip/hip_runtime.h>
#include <hip/hip_bf16.h>
#include <math.h>

// Graph attention layer, fused:
//   CSR build (count -> scan -> scatter r1), then one pass per node:
//   wave holds embs[n] row in regs, gathers embs[r1] rows, computes dot via
//   butterfly reduce, online softmax, weighted accumulation. 2 waves/node,
//   8-edge batches for ILP.

#define NEG_INF (-INFINITY)

// ---------------- kernel 1: degree counts ----------------------------------
__global__ void count_kernel(const int2* __restrict__ ratings,
                             int* __restrict__ counts,
                             int n_edges) {
    int e = blockIdx.x * blockDim.x + threadIdx.x;
    if (e >= n_edges) return;
    int r0 = ratings[e].x;
    atomicAdd(&counts[r0], 1);
}

// ---------------- kernel 2: single-block scan (1024 thr x 10 elems) --------
__global__ __launch_bounds__(1024) void scan_kernel(const int* __restrict__ counts,
                            int* __restrict__ offsets,
                            int* __restrict__ cursor,
                            int n) {
    const int K = 10;
    __shared__ int lds_ws[16];   // per-wave sums
    __shared__ int lds_wp[16];   // per-wave inclusive prefixes
    int tid  = threadIdx.x;
    int lane = tid & 63;
    int wid  = tid >> 6;
    int idx0 = tid * K;
    int c[K];
    int local = 0;
    #pragma unroll
    for (int k = 0; k < K; ++k) {
        int i = idx0 + k;
        c[k] = (i < n) ? counts[i] : 0;
        local += c[k];
    }
    // wave inclusive scan
    int incl = local;
    #pragma unroll
    for (int off = 1; off < 64; off <<= 1) {
        int t = __shfl_up(incl, off, 64);
        if (lane >= off) incl += t;
    }
    if (lane == 63) lds_ws[wid] = incl;
    __syncthreads();
    if (wid == 0 && lane < 16) {
        int wv = lds_ws[lane];
        #pragma unroll
        for (int off = 1; off < 16; off <<= 1) {
            int t = __shfl_up(wv, off, 64);
            if (lane >= off) wv += t;
        }
        lds_wp[lane] = wv;
    }
    __syncthreads();
    int wave_excl = (wid > 0) ? lds_wp[wid - 1] : 0;
    int run = wave_excl + (incl - local);   // exclusive prefix for this thread
    #pragma unroll
    for (int k = 0; k < K; ++k) {
        int i = idx0 + k;
        if (i < n) {
            offsets[i] = run;
            cursor[i]  = run;
            run += c[k];
        }
    }
    if (tid == 0) offsets[n] = lds_wp[15];
}

// ---------------- kernel 3: scatter r1 into CSR order ----------------------
__global__ void scatter_kernel(const int2* __restrict__ ratings,
                               int* __restrict__ cursor,
                               int* __restrict__ r1s,
                               int n_edges) {
    int e = blockIdx.x * blockDim.x + threadIdx.x;
    if (e >= n_edges) return;
    int2 r = ratings[e];
    int pos = atomicAdd(&cursor[r.x], 1);
    r1s[pos] = r.y;
}

// ---------------- kernel 4: fused dot + online softmax + weighted sum ------
// block = 256 threads = 4 waves = 2 nodes (2 waves per node).
__global__ __launch_bounds__(256) void node_kernel(const float* __restrict__ embs,
                            const int* __restrict__ r1s,
                            const int* __restrict__ offsets,
                            float* __restrict__ out,
                            int node_num) {
    __shared__ float s_acc[2][128];  // wave-1 partial acc per node slot
    __shared__ float s_ml[2][2];     // wave-1 m, l per node slot

    int tid   = threadIdx.x;
    int lane  = tid & 63;
    int wid   = tid >> 6;        // 0..3
    int slot  = wid >> 1;        // node slot in block: 0..1
    int w     = wid & 1;         // which half-wave of the node
    int n     = blockIdx.x * 2 + slot;
    bool valid = (n < node_num);
    int nc    = valid ? n : 0;

    float2 av = ((const float2*)(embs + (size_t)nc * 128))[lane];
    int start = valid ? offsets[nc] : 0;
    int end   = valid ? offsets[nc + 1] : 0;

    float m = NEG_INF;
    float l = 0.f;
    float2 acc = make_float2(0.f, 0.f);

    for (int base = start + w * 8; base < end; base += 16) {
        int cnt = end - base;            // >= 1
        int   r1[8];
        float2 v[8];
        float s[8];
        #pragma unroll
        for (int j = 0; j < 8; ++j)
            r1[j] = (j < cnt) ? r1s[base + j] : 0;
        #pragma unroll
        for (int j = 0; j < 8; ++j)
            v[j] = ((const float2*)(embs + (size_t)r1[j] * 128))[lane];
        #pragma unroll
        for (int j = 0; j < 8; ++j)
            s[j] = fmaf(v[j].x, av.x, v[j].y * av.y);
        #pragma unroll
        for (int j = 0; j < 8; ++j) {
            #pragma unroll
            for (int off = 1; off < 64; off <<= 1)
                s[j] += __shfl_xor(s[j], off, 64);
        }
        float bmax = NEG_INF;
        #pragma unroll
        for (int j = 0; j < 8; ++j)
            if (j < cnt) bmax = fmaxf(bmax, s[j]);
        float m_new = fmaxf(m, bmax);
        float alpha = (m == NEG_INF) ? 0.f : __expf(m - m_new);
        l *= alpha; acc.x *= alpha; acc.y *= alpha;
        #pragma unroll
        for (int j = 0; j < 8; ++j) {
            float p = (j < cnt) ? __expf(s[j] - m_new) : 0.f;
            l += p;
            acc.x = fmaf(p, v[j].x, acc.x);
            acc.y = fmaf(p, v[j].y, acc.y);
        }
        m = m_new;
    }

    // wave 1 publishes its partial state
    if (w == 1) {
        s_acc[slot][2 * lane]     = acc.x;
        s_acc[slot][2 * lane + 1] = acc.y;
        if (lane == 0) { s_ml[slot][0] = m; s_ml[slot][1] = l; }
    }
    __syncthreads();
    if (w == 0 && valid) {
        float m1 = s_ml[slot][0];
        float l1 = s_ml[slot][1];
        float ms = fmaxf(m, m1);
        float ox = 0.f, oy = 0.f;
        if (ms != NEG_INF) {
            float a0 = (m  == NEG_INF) ? 0.f : __expf(m  - ms);
            float a1 = (m1 == NEG_INF) ? 0.f : __expf(m1 - ms);
            float L  = l * a0 + l1 * a1;
            float inv = 1.f / L;
            ox = (acc.x * a0 + s_acc[slot][2 * lane]     * a1) * inv;
            oy = (acc.y * a0 + s_acc[slot][2 * lane + 1] * a1) * inv;
        }
        ((float2*)(out + (size_t)n * 128))[lane] = make_float2(ox, oy);
    }
}

// ---------------------------------------------------------------------------
extern "C" void kernel_launch(void* const* d_in, const int* in_sizes, int n_in,
                              void* d_out, int out_size, void* d_ws, size_t ws_size,
                              hipStream_t stream) {
    const float* embs    = (const float*)d_in[0];
    const int*   ratings = (const int*)d_in[1];
    const int d        = 128;
    const int node_num = in_sizes[0] / d;
    const int n_edges  = in_sizes[1] / 2;
    float* out = (float*)d_out;

    auto align256 = [](size_t x) { return (x + 255) & ~(size_t)255; };
    char* ws = (char*)d_ws;
    int* counts  = (int*)ws;  ws += align256((size_t)node_num * 4);
    int* offsets = (int*)ws;  ws += align256((size_t)(node_num + 1) * 4);
    int* cursor  = (int*)ws;  ws += align256((size_t)node_num * 4);
    int* r1s     = (int*)ws;  ws += align256((size_t)n_edges * 4);

    hipMemsetAsync(counts, 0, (size_t)node_num * 4, stream);

    {
        int threads = 256;
        int blocks = (n_edges + threads - 1) / threads;
        count_kernel<<<blocks, threads, 0, stream>>>((const int2*)ratings, counts, n_edges);
    }
    scan_kernel<<<1, 1024, 0, stream>>>(counts, offsets, cursor, node_num);
    {
        int threads = 256;
        int blocks = (n_edges + threads - 1) / threads;
        scatter_kernel<<<blocks, threads, 0, stream>>>((const int2*)ratings, cursor, r1s, n_edges);
    }
    {
        int blocks = (node_num + 1) / 2;   // 2 nodes per 256-thread block
        node_kernel<<<blocks, 256, 0, stream>>>(embs, r1s, offsets, out, node_num);
    }
}

// Round 3
// 151.644 us; speedup vs baseline: 2.3290x; 1.3691x over previous
//
#include <hip/hip_runtime.h>
#include <hip/hip_bf16.h>
#include <math.h>

// Graph attention layer, fused:
//   CSR build (count+rank -> scan -> atomic-free scatter of r1), then one
//   wave per node: 4 groups of 16 lanes, each group owns an edge stream.
//   Per edge: 2x dwordx4 gather (8 floats/lane over 16 lanes = full 128-d
//   row), 8-FMA dot partial, 4-step shfl_xor reduce (amortized across the 4
//   groups in one wave instruction), online softmax, weighted accumulate.
//   Final: merge 4 group states via shfl_xor 16/32.

#define NEG_INF (-INFINITY)

// ---------------- kernel 1: degree counts + per-edge rank ------------------
__global__ void count_kernel(const int2* __restrict__ ratings,
                             int* __restrict__ counts,
                             int* __restrict__ rank,
                             int n_edges) {
    int e = blockIdx.x * blockDim.x + threadIdx.x;
    if (e >= n_edges) return;
    int r0 = ratings[e].x;
    rank[e] = atomicAdd(&counts[r0], 1);
}

// ---------------- kernel 2: single-block scan (1024 thr x 10 elems) --------
__global__ __launch_bounds__(1024) void scan_kernel(const int* __restrict__ counts,
                            int* __restrict__ offsets,
                            int n) {
    const int K = 10;
    __shared__ int lds_ws[16];
    __shared__ int lds_wp[16];
    int tid  = threadIdx.x;
    int lane = tid & 63;
    int wid  = tid >> 6;
    int idx0 = tid * K;
    int c[K];
    int local = 0;
    #pragma unroll
    for (int k = 0; k < K; ++k) {
        int i = idx0 + k;
        c[k] = (i < n) ? counts[i] : 0;
        local += c[k];
    }
    int incl = local;
    #pragma unroll
    for (int off = 1; off < 64; off <<= 1) {
        int t = __shfl_up(incl, off, 64);
        if (lane >= off) incl += t;
    }
    if (lane == 63) lds_ws[wid] = incl;
    __syncthreads();
    if (wid == 0 && lane < 16) {
        int wv = lds_ws[lane];
        #pragma unroll
        for (int off = 1; off < 16; off <<= 1) {
            int t = __shfl_up(wv, off, 64);
            if (lane >= off) wv += t;
        }
        lds_wp[lane] = wv;
    }
    __syncthreads();
    int wave_excl = (wid > 0) ? lds_wp[wid - 1] : 0;
    int run = wave_excl + (incl - local);
    #pragma unroll
    for (int k = 0; k < K; ++k) {
        int i = idx0 + k;
        if (i < n) {
            offsets[i] = run;
            run += c[k];
        }
    }
    if (tid == 0) offsets[n] = lds_wp[15];
}

// ---------------- kernel 3: atomic-free scatter of r1 ----------------------
__global__ void scatter_kernel(const int2* __restrict__ ratings,
                               const int* __restrict__ offsets,
                               const int* __restrict__ rank,
                               int* __restrict__ r1s,
                               int n_edges) {
    int e = blockIdx.x * blockDim.x + threadIdx.x;
    if (e >= n_edges) return;
    int2 r = ratings[e];
    int pos = offsets[r.x] + rank[e];
    r1s[pos] = r.y;
}

// ---------------- kernel 4: fused node pass --------------------------------
// 1 wave per node; wave = 4 groups x 16 lanes; lane t in group holds
// features [t*4, t*4+4) and [64+t*4, 64+t*4+4).
__global__ __launch_bounds__(256) void node_kernel(const float* __restrict__ embs,
                            const int* __restrict__ r1s,
                            const int* __restrict__ offsets,
                            float* __restrict__ out,
                            int node_num) {
    int tid  = threadIdx.x;
    int lane = tid & 63;
    int g    = lane >> 4;        // group 0..3
    int t    = lane & 15;        // lane-in-group
    int n    = blockIdx.x * 4 + (tid >> 6);
    if (n >= node_num) return;

    const float4* row_n = (const float4*)(embs + (size_t)n * 128);
    float4 av0 = row_n[t];
    float4 av1 = row_n[16 + t];
    int start = offsets[n];
    int end   = offsets[n + 1];

    float  m = NEG_INF;
    float  l = 0.f;
    float4 acc0 = make_float4(0.f, 0.f, 0.f, 0.f);
    float4 acc1 = make_float4(0.f, 0.f, 0.f, 0.f);

    for (int base = start; base < end; base += 16) {
        // group g handles edges base + b*4 + g, b = 0..3
        bool  valid[4];
        int   r1[4];
        #pragma unroll
        for (int b = 0; b < 4; ++b) {
            int idx = base + b * 4 + g;
            valid[b] = (idx < end);
            r1[b] = valid[b] ? r1s[idx] : 0;
        }
        float4 v0[4], v1[4];
        #pragma unroll
        for (int b = 0; b < 4; ++b) {
            const float4* row = (const float4*)(embs + (size_t)r1[b] * 128);
            v0[b] = row[t];
            v1[b] = row[16 + t];
        }
        float s[4];
        #pragma unroll
        for (int b = 0; b < 4; ++b) {
            float d = v0[b].x * av0.x;
            d = fmaf(v0[b].y, av0.y, d);
            d = fmaf(v0[b].z, av0.z, d);
            d = fmaf(v0[b].w, av0.w, d);
            d = fmaf(v1[b].x, av1.x, d);
            d = fmaf(v1[b].y, av1.y, d);
            d = fmaf(v1[b].z, av1.z, d);
            d = fmaf(v1[b].w, av1.w, d);
            s[b] = d;
        }
        // reduce within 16-lane group (xor 1,2,4,8 keeps lanes in-group);
        // one shfl instruction serves all 4 groups at once.
        #pragma unroll
        for (int b = 0; b < 4; ++b) {
            #pragma unroll
            for (int off = 1; off < 16; off <<= 1)
                s[b] += __shfl_xor(s[b], off, 64);
            if (!valid[b]) s[b] = NEG_INF;
        }
        float bmax = fmaxf(fmaxf(s[0], s[1]), fmaxf(s[2], s[3]));
        float m_new = fmaxf(m, bmax);
        float alpha = (m == NEG_INF) ? 0.f : __expf(m - m_new);
        l *= alpha;
        acc0.x *= alpha; acc0.y *= alpha; acc0.z *= alpha; acc0.w *= alpha;
        acc1.x *= alpha; acc1.y *= alpha; acc1.z *= alpha; acc1.w *= alpha;
        #pragma unroll
        for (int b = 0; b < 4; ++b) {
            float p = valid[b] ? __expf(s[b] - m_new) : 0.f;
            l += p;
            acc0.x = fmaf(p, v0[b].x, acc0.x);
            acc0.y = fmaf(p, v0[b].y, acc0.y);
            acc0.z = fmaf(p, v0[b].z, acc0.z);
            acc0.w = fmaf(p, v0[b].w, acc0.w);
            acc1.x = fmaf(p, v1[b].x, acc1.x);
            acc1.y = fmaf(p, v1[b].y, acc1.y);
            acc1.z = fmaf(p, v1[b].z, acc1.z);
            acc1.w = fmaf(p, v1[b].w, acc1.w);
        }
        m = m_new;
    }

    // merge the 4 group states (xor 16, then xor 32)
    #pragma unroll
    for (int off = 16; off <= 32; off <<= 1) {
        float m_o = __shfl_xor(m, off, 64);
        float l_o = __shfl_xor(l, off, 64);
        float4 b0, b1;
        b0.x = __shfl_xor(acc0.x, off, 64);
        b0.y = __shfl_xor(acc0.y, off, 64);
        b0.z = __shfl_xor(acc0.z, off, 64);
        b0.w = __shfl_xor(acc0.w, off, 64);
        b1.x = __shfl_xor(acc1.x, off, 64);
        b1.y = __shfl_xor(acc1.y, off, 64);
        b1.z = __shfl_xor(acc1.z, off, 64);
        b1.w = __shfl_xor(acc1.w, off, 64);
        float ms = fmaxf(m, m_o);
        float a  = (m   == NEG_INF) ? 0.f : __expf(m   - ms);
        float ao = (m_o == NEG_INF) ? 0.f : __expf(m_o - ms);
        l = l * a + l_o * ao;
        acc0.x = acc0.x * a + b0.x * ao;
        acc0.y = acc0.y * a + b0.y * ao;
        acc0.z = acc0.z * a + b0.z * ao;
        acc0.w = acc0.w * a + b0.w * ao;
        acc1.x = acc1.x * a + b1.x * ao;
        acc1.y = acc1.y * a + b1.y * ao;
        acc1.z = acc1.z * a + b1.z * ao;
        acc1.w = acc1.w * a + b1.w * ao;
        m = ms;
    }

    float inv = (l > 0.f) ? 1.f / l : 0.f;
    if (g == 0) {
        float4* orow = (float4*)(out + (size_t)n * 128);
        orow[t]      = make_float4(acc0.x * inv, acc0.y * inv, acc0.z * inv, acc0.w * inv);
        orow[16 + t] = make_float4(acc1.x * inv, acc1.y * inv, acc1.z * inv, acc1.w * inv);
    }
}

// ---------------------------------------------------------------------------
extern "C" void kernel_launch(void* const* d_in, const int* in_sizes, int n_in,
                              void* d_out, int out_size, void* d_ws, size_t ws_size,
                              hipStream_t stream) {
    const float* embs    = (const float*)d_in[0];
    const int*   ratings = (const int*)d_in[1];
    const int d        = 128;
    const int node_num = in_sizes[0] / d;
    const int n_edges  = in_sizes[1] / 2;
    float* out = (float*)d_out;

    auto align256 = [](size_t x) { return (x + 255) & ~(size_t)255; };
    char* ws = (char*)d_ws;
    int* counts  = (int*)ws;  ws += align256((size_t)node_num * 4);
    int* offsets = (int*)ws;  ws += align256((size_t)(node_num + 1) * 4);
    int* rank    = (int*)ws;  ws += align256((size_t)n_edges * 4);
    int* r1s     = (int*)ws;  ws += align256((size_t)n_edges * 4);

    hipMemsetAsync(counts, 0, (size_t)node_num * 4, stream);

    {
        int threads = 256;
        int blocks = (n_edges + threads - 1) / threads;
        count_kernel<<<blocks, threads, 0, stream>>>((const int2*)ratings, counts, rank, n_edges);
    }
    scan_kernel<<<1, 1024, 0, stream>>>(counts, offsets, node_num);
    {
        int threads = 256;
        int blocks = (n_edges + threads - 1) / threads;
        scatter_kernel<<<blocks, threads, 0, stream>>>((const int2*)ratings, offsets, rank, r1s, n_edges);
    }
    {
        int blocks = (node_num + 3) / 4;   // 4 nodes (waves) per 256-thread block
        node_kernel<<<blocks, 256, 0, stream>>>(embs, r1s, offsets, out, node_num);
    }
}